// Round 10
// baseline (645.297 us; speedup 1.0000x reference)
//
#include <hip/hip_runtime.h>
#include <cstdint>
#include <cstddef>

// Problem constants (fixed by reference: B=4, T=2048, D=1024, H=16, DH=64, K=4)
#define TSEQ 2048
#define NB   4
#define NH   16
#define MM   (NB * TSEQ)     // 8192 rows
#define KK   1024            // inner dim for all big GEMMs
#define NCAT 4224            // 1024*4 (q,k,v,g) + 16 (a) + 16 (b) + 96 pad -> 33 tiles of 128
#define LSTR 40              // LDS row stride (elems): 80B row -> 16B-aligned, 2-way banks (was 32: 8-way)

typedef __attribute__((ext_vector_type(8))) __bf16 bf16x8;
typedef __attribute__((ext_vector_type(4))) float f32x4;
typedef __attribute__((ext_vector_type(4))) int   int4v;

__device__ __forceinline__ unsigned short f2bf(float f) {
  unsigned int u = __float_as_uint(f);
  u += 0x7fffu + ((u >> 16) & 1u);          // round-to-nearest-even
  return (unsigned short)(u >> 16);
}
__device__ __forceinline__ float bf2f(unsigned short h) {
  return __uint_as_float(((unsigned int)h) << 16);
}
__device__ __forceinline__ float sigmoidf_(float x) { return 1.0f / (1.0f + expf(-x)); }
__device__ __forceinline__ float siluf_(float x)    { return x / (1.0f + expf(-x)); }

__device__ __forceinline__ uint32_t packsplit(float x) {
  unsigned short h = f2bf(x);
  unsigned short l = f2bf(x - bf2f(h));
  return ((uint32_t)h << 16) | (uint32_t)l;
}

union BF8 { bf16x8 v; unsigned short s[8]; };

__device__ __forceinline__ void frag_from_packed(const uint32_t* p, bf16x8& hi, bf16x8& lo) {
  int4v a = *(const int4v*)p;
  int4v b = *(const int4v*)(p + 4);
  BF8 H, L;
#pragma unroll
  for (int e = 0; e < 4; ++e) {
    uint32_t ua = ((const uint32_t*)&a)[e];
    uint32_t ub = ((const uint32_t*)&b)[e];
    H.s[e]     = (unsigned short)(ua >> 16);
    L.s[e]     = (unsigned short)(ua & 0xffffu);
    H.s[e + 4] = (unsigned short)(ub >> 16);
    L.s[e + 4] = (unsigned short)(ub & 0xffffu);
  }
  hi = H.v; lo = L.v;
}

__device__ __forceinline__ f32x4 mfma3(bf16x8 ah, bf16x8 al, bf16x8 bh, bf16x8 bl, f32x4 acc) {
  acc = __builtin_amdgcn_mfma_f32_16x16x32_bf16(ah, bh, acc, 0, 0, 0);
  acc = __builtin_amdgcn_mfma_f32_16x16x32_bf16(ah, bl, acc, 0, 0, 0);
  acc = __builtin_amdgcn_mfma_f32_16x16x32_bf16(al, bh, acc, 0, 0, 0);
  return acc;
}

// ---------------- split fp32 -> bf16 hi/lo (vectorized x8) ----------------
__global__ void k_split(const float* __restrict__ x, unsigned short* __restrict__ hi,
                        unsigned short* __restrict__ lo, int n) {
  int idx = (blockIdx.x * blockDim.x + threadIdx.x) * 8;
  if (idx >= n) return;
  float v[8];
  *(float4*)&v[0] = *(const float4*)(x + idx);
  *(float4*)&v[4] = *(const float4*)(x + idx + 4);
  unsigned short hs[8], ls[8];
#pragma unroll
  for (int e = 0; e < 8; ++e) {
    unsigned short h = f2bf(v[e]);
    hs[e] = h;
    ls[e] = f2bf(v[e] - bf2f(h));
  }
  *(int4v*)(hi + idx) = *(const int4v*)hs;
  *(int4v*)(lo + idx) = *(const int4v*)ls;
}

// ---------------- build Wcat hi/lo (vectorized x8) ----------------
__global__ void k_build_wcat(const float* __restrict__ Wq, const float* __restrict__ Wk,
                             const float* __restrict__ Wv, const float* __restrict__ Wg,
                             const float* __restrict__ Wa, const float* __restrict__ Wb,
                             unsigned short* __restrict__ hi, unsigned short* __restrict__ lo) {
  int idx = (blockIdx.x * blockDim.x + threadIdx.x) * 8;
  if (idx >= NCAT * KK) return;
  int row = idx >> 10, col = idx & 1023;
  const float* src = nullptr;
  if      (row < 1024) src = Wq + idx;
  else if (row < 2048) src = Wk + (idx - 1024 * 1024);
  else if (row < 3072) src = Wv + (idx - 2048 * 1024);
  else if (row < 4096) src = Wg + (idx - 3072 * 1024);
  else if (row < 4112) src = Wa + (row - 4096) * 1024 + col;
  else if (row < 4128) src = Wb + (row - 4112) * 1024 + col;
  float v[8];
  if (src) {
    *(float4*)&v[0] = *(const float4*)src;
    *(float4*)&v[4] = *(const float4*)(src + 4);
  } else {
#pragma unroll
    for (int e = 0; e < 8; ++e) v[e] = 0.0f;
  }
  unsigned short hs[8], ls[8];
#pragma unroll
  for (int e = 0; e < 8; ++e) {
    unsigned short h = f2bf(v[e]);
    hs[e] = h;
    ls[e] = f2bf(v[e] - bf2f(h));
  }
  *(int4v*)(hi + idx) = *(const int4v*)hs;
  *(int4v*)(lo + idx) = *(const int4v*)ls;
}

// ---------------- split-bf16 MFMA GEMM ----------------
// ROUND-CHANGE: LDS staging row stride 32 -> 40 elems (80B). Reg-staged (not
// global_load_lds) so padding is legal. ds_read_b128 fragment reads were 8-way
// bank conflicts (row byte-stride 64 -> banks {b,b+16}); at 80B stride 16 rows
// span 8 distinct banks x 2 lanes = 2-way = free. Rows stay 16B-aligned.
__global__ __launch_bounds__(256, 2)
void k_gemm(const unsigned short* __restrict__ Ahi, const unsigned short* __restrict__ Alo,
            const unsigned short* __restrict__ Bhi, const unsigned short* __restrict__ Blo,
            int Kdim, int mode,
            float* __restrict__ Qb, float* __restrict__ Kb, float* __restrict__ Vb,
            float* __restrict__ Gb, float* __restrict__ Ab, float* __restrict__ Bbuf,
            const float* __restrict__ bg, const float* __restrict__ ba, const float* __restrict__ bb,
            float* __restrict__ Out) {
  __shared__ __align__(16) unsigned short As_hi[128 * LSTR];
  __shared__ __align__(16) unsigned short As_lo[128 * LSTR];
  __shared__ __align__(16) unsigned short Bs_hi[128 * LSTR];
  __shared__ __align__(16) unsigned short Bs_lo[128 * LSTR];

  const int tid  = threadIdx.x;
  const int lane = tid & 63;
  const int l15  = lane & 15;
  const int quad = lane >> 4;
  const int wid  = tid >> 6;
  const int wm   = (wid >> 1) * 64;
  const int wn   = (wid & 1) * 64;
  const int m0   = blockIdx.x * 128;
  const int n0   = blockIdx.y * 128;
  const int srow = tid >> 2;
  const int skc  = (tid & 3) * 8;

  f32x4 acc[4][4];
  f32x4 zero4 = {0.f, 0.f, 0.f, 0.f};
#pragma unroll
  for (int i = 0; i < 4; ++i)
#pragma unroll
    for (int j = 0; j < 4; ++j) acc[i][j] = zero4;

  const unsigned short* pa0 = Ahi + (size_t)(m0 + srow) * Kdim + skc;
  const unsigned short* pa1 = Ahi + (size_t)(m0 + srow + 64) * Kdim + skc;
  const unsigned short* pa2 = Alo + (size_t)(m0 + srow) * Kdim + skc;
  const unsigned short* pa3 = Alo + (size_t)(m0 + srow + 64) * Kdim + skc;
  const unsigned short* pb0 = Bhi + (size_t)(n0 + srow) * Kdim + skc;
  const unsigned short* pb1 = Bhi + (size_t)(n0 + srow + 64) * Kdim + skc;
  const unsigned short* pb2 = Blo + (size_t)(n0 + srow) * Kdim + skc;
  const unsigned short* pb3 = Blo + (size_t)(n0 + srow + 64) * Kdim + skc;

  for (int kt = 0; kt < Kdim; kt += 32) {
    int4v va0 = *(const int4v*)(pa0 + kt);
    int4v va1 = *(const int4v*)(pa1 + kt);
    int4v va2 = *(const int4v*)(pa2 + kt);
    int4v va3 = *(const int4v*)(pa3 + kt);
    int4v vb0 = *(const int4v*)(pb0 + kt);
    int4v vb1 = *(const int4v*)(pb1 + kt);
    int4v vb2 = *(const int4v*)(pb2 + kt);
    int4v vb3 = *(const int4v*)(pb3 + kt);
    __syncthreads();
    *(int4v*)&As_hi[srow * LSTR + skc]        = va0;
    *(int4v*)&As_hi[(srow + 64) * LSTR + skc] = va1;
    *(int4v*)&As_lo[srow * LSTR + skc]        = va2;
    *(int4v*)&As_lo[(srow + 64) * LSTR + skc] = va3;
    *(int4v*)&Bs_hi[srow * LSTR + skc]        = vb0;
    *(int4v*)&Bs_hi[(srow + 64) * LSTR + skc] = vb1;
    *(int4v*)&Bs_lo[srow * LSTR + skc]        = vb2;
    *(int4v*)&Bs_lo[(srow + 64) * LSTR + skc] = vb3;
    __syncthreads();

    bf16x8 ah[4], al[4], bh[4], bl[4];
#pragma unroll
    for (int f = 0; f < 4; ++f) {
      int ra = (wm + f * 16 + l15) * LSTR + quad * 8;
      ah[f] = *(const bf16x8*)&As_hi[ra];
      al[f] = *(const bf16x8*)&As_lo[ra];
      int rb = (wn + f * 16 + l15) * LSTR + quad * 8;
      bh[f] = *(const bf16x8*)&Bs_hi[rb];
      bl[f] = *(const bf16x8*)&Bs_lo[rb];
    }
#pragma unroll
    for (int mf = 0; mf < 4; ++mf)
#pragma unroll
      for (int nf = 0; nf < 4; ++nf) {
        acc[mf][nf] = __builtin_amdgcn_mfma_f32_16x16x32_bf16(ah[mf], bh[nf], acc[mf][nf], 0, 0, 0);
        acc[mf][nf] = __builtin_amdgcn_mfma_f32_16x16x32_bf16(ah[mf], bl[nf], acc[mf][nf], 0, 0, 0);
        acc[mf][nf] = __builtin_amdgcn_mfma_f32_16x16x32_bf16(al[mf], bh[nf], acc[mf][nf], 0, 0, 0);
      }
  }

#pragma unroll
  for (int mf = 0; mf < 4; ++mf) {
    int rowb = m0 + wm + mf * 16 + quad * 4;
#pragma unroll
    for (int nf = 0; nf < 4; ++nf) {
      int col = n0 + wn + nf * 16 + l15;
      f32x4 v = acc[mf][nf];
      if (mode == 1) {
#pragma unroll
        for (int r = 0; r < 4; ++r) Out[(size_t)(rowb + r) * 1024 + col] = v[r];
      } else {
        if (col < 1024) {
#pragma unroll
          for (int r = 0; r < 4; ++r) Qb[(size_t)(rowb + r) * 1024 + col] = v[r];
        } else if (col < 2048) {
          int c = col - 1024;
#pragma unroll
          for (int r = 0; r < 4; ++r) Kb[(size_t)(rowb + r) * 1024 + c] = v[r];
        } else if (col < 3072) {
          int c = col - 2048;
#pragma unroll
          for (int r = 0; r < 4; ++r) Vb[(size_t)(rowb + r) * 1024 + c] = v[r];
        } else if (col < 4096) {
          int c = col - 3072;
          float bgc = bg[c];
#pragma unroll
          for (int r = 0; r < 4; ++r) {
            float x = v[r] + bgc;
            Gb[(size_t)(rowb + r) * 1024 + c] = siluf_(x);
          }
        } else if (col < 4112) {
          int c = col - 4096;
          float bac = ba[c];
#pragma unroll
          for (int r = 0; r < 4; ++r) Ab[(size_t)(rowb + r) * 16 + c] = sigmoidf_(v[r] + bac);
        } else if (col < 4128) {
          int c = col - 4112;
          float bbc = bb[c];
#pragma unroll
          for (int r = 0; r < 4; ++r) Bbuf[(size_t)(rowb + r) * 16 + c] = sigmoidf_(v[r] + bbc);
        }
      }
    }
  }
}

// ---------------- k_intra: round-7 best (512 threads, grid 2048) ----------------
__global__ __launch_bounds__(512)
void k_intra(const float* __restrict__ Qb, const float* __restrict__ Kb,
             const float* __restrict__ Vb,
             const float* __restrict__ Ab, const float* __restrict__ Bb,
             const float* __restrict__ cqw, const float* __restrict__ cqb,
             const float* __restrict__ ckw, const float* __restrict__ ckb,
             const float* __restrict__ cvw, const float* __restrict__ cvb,
             uint32_t* __restrict__ A1buf, unsigned short* __restrict__ Qefbuf,
             unsigned short* __restrict__ G1buf, unsigned short* __restrict__ G2Tbuf,
             float* __restrict__ gCbuf) {
  __shared__ __align__(16) unsigned short Khi[64][72], Klo[64][72];
  __shared__ __align__(16) unsigned short Qhi[64][72], Qlo[64][72];
  __shared__ float Vf[64][65];
  __shared__ float Rf[64][65];
  __shared__ float Mm[64][68];
  __shared__ __align__(16) unsigned short Atthi[64][72];
  __shared__ __align__(16) uint32_t u0T[64][68], RTp[64][68];
  __shared__ __align__(16) unsigned short KwThi[64][72], KwTlo[64][72];
  __shared__ float lgs[64], gas[64], bss[64], wvs[64], ins[64];

  const int tid  = threadIdx.x;
  const int lane = tid & 63;
  const int w8   = tid >> 6;
  const int ws   = w8 & 3;
  const int hs   = w8 >> 2;
  const int l15  = lane & 15;
  const int quad = lane >> 4;
  const int bid  = blockIdx.x;
  const int c    = bid & 31;
  const int h    = (bid >> 5) & 15;
  const int b    = bid >> 9;
  const size_t ci = (size_t)bid;
  const int t0   = c * 64;
  const long rowBase = (long)b * 2048 + t0;
  const int ch   = h * 64 + lane;
  const f32x4 z4 = {0.f, 0.f, 0.f, 0.f};

  {
    long gr = (rowBase + lane) * 16 + h;
    float av = Ab[gr], bv = Bb[gr];
    float x = log2f(av);
#pragma unroll
    for (int off = 1; off < 64; off <<= 1) {
      float y = __shfl_up(x, off);
      if (lane >= off) x += y;
    }
    float l63 = __shfl(x, 63);
    lgs[lane] = x;
    gas[lane] = exp2f(x);
    bss[lane] = bv;
    wvs[lane] = exp2f(l63 - x) * bv;
  }

  {
    const float kc0 = ckw[ch * 4], kc1 = ckw[ch * 4 + 1], kc2 = ckw[ch * 4 + 2], kc3 = ckw[ch * 4 + 3], kcbv = ckb[ch];
    const float qc0 = cqw[ch * 4], qc1 = cqw[ch * 4 + 1], qc2 = cqw[ch * 4 + 2], qc3 = cqw[ch * 4 + 3], qcbv = cqb[ch];
    const float vc0 = cvw[ch * 4], vc1 = cvw[ch * 4 + 1], vc2 = cvw[ch * 4 + 2], vc3 = cvw[ch * 4 + 3], vcbv = cvb[ch];
    const int tb = t0 + w8 * 8;
    float kw0, kw1, kw2, qw0, qw1, qw2, vw0, vw1, vw2;
    {
      float kx[3], qx[3], vx[3];
#pragma unroll
      for (int d = 0; d < 3; ++d) {
        int tt = tb - 3 + d;
        float a = 0.f, bq = 0.f, cv = 0.f;
        if (tt >= 0) {
          long ro = ((long)b * 2048 + tt) * 1024 + ch;
          a = Kb[ro]; bq = Qb[ro]; cv = Vb[ro];
        }
        kx[d] = a; qx[d] = bq; vx[d] = cv;
      }
      kw0 = kx[0]; kw1 = kx[1]; kw2 = kx[2];
      qw0 = qx[0]; qw1 = qx[1]; qw2 = qx[2];
      vw0 = vx[0]; vw1 = vx[1]; vw2 = vx[2];
    }
#pragma unroll
    for (int lt = 0; lt < 8; ++lt) {
      const int s = w8 * 8 + lt;
      const long ro = (rowBase + s) * 1024 + ch;
      float kr = Kb[ro], qr = Qb[ro], vr = Vb[ro];
      float kcv = kcbv + kc0 * kw0 + kc1 * kw1 + kc2 * kw2 + kc3 * kr;
      float qcv = qcbv + qc0 * qw0 + qc1 * qw1 + qc2 * qw2 + qc3 * qr;
      float vcv = vcbv + vc0 * vw0 + vc1 * vw1 + vc2 * vw2 + vc3 * vr;
      kw0 = kw1; kw1 = kw2; kw2 = kr;
      qw0 = qw1; qw1 = qw2; qw2 = qr;
      vw0 = vw1; vw1 = vw2; vw2 = vr;
      float kv = siluf_(kcv), qv = siluf_(qcv), vv = siluf_(vcv);
      uint32_t kp_ = packsplit(kv);
      uint32_t qp_ = packsplit(qv);
      Khi[s][lane] = (unsigned short)(kp_ >> 16); Klo[s][lane] = (unsigned short)(kp_ & 0xffffu);
      Qhi[s][lane] = (unsigned short)(qp_ >> 16); Qlo[s][lane] = (unsigned short)(qp_ & 0xffffu);
      Vf[s][lane] = vv;
    }
  }
  __syncthreads();                                     // B1

  f32x4 accT[4];
#pragma unroll
  for (int nt = 0; nt < 4; ++nt) accT[nt] = z4;
#pragma unroll
  for (int ks = 0; ks < 2; ++ks) {
    bf16x8 ah, al;
    if (hs == 0) {
      ah = *(const bf16x8*)&Khi[ws * 16 + l15][ks * 32 + quad * 8];
      al = *(const bf16x8*)&Klo[ws * 16 + l15][ks * 32 + quad * 8];
    } else {
      ah = *(const bf16x8*)&Qhi[ws * 16 + l15][ks * 32 + quad * 8];
      al = *(const bf16x8*)&Qlo[ws * 16 + l15][ks * 32 + quad * 8];
    }
#pragma unroll
    for (int nt = 0; nt < 4; ++nt) {
      bf16x8 bh = *(const bf16x8*)&Khi[nt * 16 + l15][ks * 32 + quad * 8];
      bf16x8 bl = *(const bf16x8*)&Klo[nt * 16 + l15][ks * 32 + quad * 8];
      accT[nt] = mfma3(ah, al, bh, bl, accT[nt]);
    }
  }
  if (hs == 0) {
#pragma unroll
    for (int nt = 0; nt < 4; ++nt)
      if (nt == ws) {
#pragma unroll
        for (int r = 0; r < 4; ++r)
          if (l15 == quad * 4 + r) ins[nt * 16 + l15] = rsqrtf(fmaxf(accT[nt][r], 1e-24f));
      }
  }
  __syncthreads();                                     // B2

  {
    if (hs == 0) {
#pragma unroll
      for (int nt = 0; nt < 4; ++nt) {
        int sc = nt * 16 + l15;
        float insc = ins[sc], lgc = lgs[sc], bsc = bss[sc];
#pragma unroll
        for (int r = 0; r < 4; ++r) {
          int sr = ws * 16 + quad * 4 + r;
          Mm[sr][sc] = (sc < sr) ? exp2f(lgs[sr] - lgc) * bsc * ins[sr] * insc * accT[nt][r] : 0.f;
        }
      }
    } else {
#pragma unroll
      for (int nt = 0; nt < 4; ++nt) {
        int sc = nt * 16 + l15;
        float insc = ins[sc], lgc = lgs[sc], bsc = bss[sc];
#pragma unroll
        for (int r = 0; r < 4; ++r) {
          int sr = ws * 16 + quad * 4 + r;
          Atthi[sr][sc] = f2bf((sc <= sr) ? exp2f(lgs[sr] - lgc) * bsc * insc * accT[nt][r] : 0.f);
        }
      }
    }
    int s = w8 * 8 + (lane & 7);
    int jb = (lane >> 3) * 8;
    float rsc = gas[s] * ins[s];
    float wsc = wvs[s] * ins[s];
    BF8 H0, L0;
    H0.v = *(const bf16x8*)&Khi[s][jb];
    L0.v = *(const bf16x8*)&Klo[s][jb];
#pragma unroll
    for (int e = 0; e < 8; ++e) {
      float kv = bf2f(H0.s[e]) + bf2f(L0.s[e]);
      Rf[s][jb + e] = kv * rsc;
      uint32_t p0 = packsplit(kv * wsc);
      KwThi[jb + e][s] = (unsigned short)(p0 >> 16);
      KwTlo[jb + e][s] = (unsigned short)(p0 & 0xffffu);
    }
  }
  if (tid == 0) gCbuf[ci] = gas[63];
  __syncthreads();                                     // B3

  if (w8 < 2) {
    float* RHS = (w8 == 0) ? &Vf[0][0] : &Rf[0][0];
    const int i = lane;
    float u[64];
#pragma unroll
    for (int d = 0; d < 4; ++d) {
      const int base = d * 16;
#pragma unroll
      for (int r2 = 0; r2 < 16; ++r2) {
        const int s = base + r2;
        float acc = RHS[s * 65 + i];
#pragma unroll
        for (int r = 0; r < r2; ++r) acc = fmaf(-Mm[s][base + r], u[base + r], acc);
        u[s] = acc;
        RHS[s * 65 + i] = acc;
      }
      if (d < 3) {
#pragma unroll 1
        for (int s = base + 16; s < 64; ++s) {
          f32x4 m0 = *(const f32x4*)&Mm[s][base];
          f32x4 m1 = *(const f32x4*)&Mm[s][base + 4];
          f32x4 m2 = *(const f32x4*)&Mm[s][base + 8];
          f32x4 m3 = *(const f32x4*)&Mm[s][base + 12];
          float a0 = m0[0] * u[base + 0] + m0[1] * u[base + 1] + m0[2] * u[base + 2] + m0[3] * u[base + 3];
          float a1 = m1[0] * u[base + 4] + m1[1] * u[base + 5] + m1[2] * u[base + 6] + m1[3] * u[base + 7];
          float a2 = m2[0] * u[base + 8] + m2[1] * u[base + 9] + m2[2] * u[base + 10] + m2[3] * u[base + 11];
          float a3 = m3[0] * u[base + 12] + m3[1] * u[base + 13] + m3[2] * u[base + 14] + m3[3] * u[base + 15];
          RHS[s * 65 + i] = RHS[s * 65 + i] - ((a0 + a1) + (a2 + a3));
        }
      }
    }
  }
  __syncthreads();                                     // B4

#pragma unroll
  for (int r = 0; r < 8; ++r) {
    int i = w8 * 8 + r;
    u0T[i][lane] = packsplit(Vf[lane][i]);
    RTp[i][lane] = packsplit(Rf[lane][i]);
  }
  __syncthreads();                                     // B5

  if (hs == 0) {
    {
      f32x4 acc[4];
#pragma unroll
      for (int nt = 0; nt < 4; ++nt) acc[nt] = z4;
#pragma unroll
      for (int ks = 0; ks < 2; ++ks) {
        bf16x8 ta = *(const bf16x8*)&Atthi[ws * 16 + l15][ks * 32 + quad * 8];
#pragma unroll
        for (int nt = 0; nt < 4; ++nt) {
          bf16x8 uh, ul;
          frag_from_packed(&u0T[nt * 16 + l15][ks * 32 + quad * 8], uh, ul);
          acc[nt] = __builtin_amdgcn_mfma_f32_16x16x32_bf16(ta, uh, acc[nt], 0, 0, 0);
          acc[nt] = __builtin_amdgcn_mfma_f32_16x16x32_bf16(ta, ul, acc[nt], 0, 0, 0);
        }
      }
#pragma unroll
      for (int nt = 0; nt < 4; ++nt)
#pragma unroll
        for (int r = 0; r < 4; ++r) {
          int t = ws * 16 + quad * 4 + r, i = nt * 16 + l15;
          A1buf[ci * 4096 + t * 64 + i] = packsplit(acc[nt][r]);
        }
    }
    {
      f32x4 acc[4];
#pragma unroll
      for (int nt = 0; nt < 4; ++nt) acc[nt] = z4;
#pragma unroll
      for (int ks = 0; ks < 2; ++ks) {
        bf16x8 ta = *(const bf16x8*)&Atthi[ws * 16 + l15][ks * 32 + quad * 8];
#pragma unroll
        for (int nt = 0; nt < 4; ++nt) {
          bf16x8 rh, rl;
          frag_from_packed(&RTp[nt * 16 + l15][ks * 32 + quad * 8], rh, rl);
          acc[nt] = __builtin_amdgcn_mfma_f32_16x16x32_bf16(ta, rh, acc[nt], 0, 0, 0);
          acc[nt] = __builtin_amdgcn_mfma_f32_16x16x32_bf16(ta, rl, acc[nt], 0, 0, 0);
        }
      }
#pragma unroll
      for (int nt = 0; nt < 4; ++nt)
#pragma unroll
        for (int r = 0; r < 4; ++r) {
          int t = ws * 16 + quad * 4 + r, j = nt * 16 + l15;
          float q = bf2f(Qhi[t][j]) + bf2f(Qlo[t][j]);
          Qefbuf[ci * 4096 + t * 64 + j] = f2bf(gas[t] * q - acc[nt][r]);
        }
    }
  } else {
    {
      f32x4 acc[4];
#pragma unroll
      for (int nt = 0; nt < 4; ++nt) acc[nt] = z4;
#pragma unroll
      for (int ks = 0; ks < 2; ++ks) {
        bf16x8 uh, ul;
        frag_from_packed(&u0T[ws * 16 + l15][ks * 32 + quad * 8], uh, ul);
#pragma unroll
        for (int nt = 0; nt < 4; ++nt) {
          bf16x8 kh = *(const bf16x8*)&KwThi[nt * 16 + l15][ks * 32 + quad * 8];
          bf16x8 kl = *(const bf16x8*)&KwTlo[nt * 16 + l15][ks * 32 + quad * 8];
          acc[nt] = mfma3(uh, ul, kh, kl, acc[nt]);
        }
      }
#pragma unroll
      for (int nt = 0; nt < 4; ++nt)
#pragma unroll
        for (int r = 0; r < 4; ++r) {
          int i = ws * 16 + quad * 4 + r, j = nt * 16 + l15;
          G1buf[ci * 4096 + i * 64 + j] = f2bf(acc[nt][r]);
        }
    }
    {
      f32x4 acc[4];
#pragma unroll
      for (int nt = 0; nt < 4; ++nt) acc[nt] = z4;
#pragma unroll
      for (int ks = 0; ks < 2; ++ks) {
        bf16x8 rh, rl;
        frag_from_packed(&RTp[ws * 16 + l15][ks * 32 + quad * 8], rh, rl);
#pragma unroll
        for (int nt = 0; nt < 4; ++nt) {
          bf16x8 kh = *(const bf16x8*)&KwThi[nt * 16 + l15][ks * 32 + quad * 8];
          bf16x8 kl = *(const bf16x8*)&KwTlo[nt * 16 + l15][ks * 32 + quad * 8];
          acc[nt] = mfma3(rh, rl, kh, kl, acc[nt]);
        }
      }
#pragma unroll
      for (int nt = 0; nt < 4; ++nt) {
        int j = nt * 16 + l15;
        int mb = ws * 16 + quad * 4;
        uint32_t lo32 = (uint32_t)f2bf(acc[nt][0]) | ((uint32_t)f2bf(acc[nt][1]) << 16);
        uint32_t hi32 = (uint32_t)f2bf(acc[nt][2]) | ((uint32_t)f2bf(acc[nt][3]) << 16);
        uint32_t* dst = (uint32_t*)&G2Tbuf[ci * 4096 + j * 64 + mb];
        dst[0] = lo32; dst[1] = hi32;
      }
    }
  }
}

// ---------------- k_serial: 32-step recurrence, row-split 4x, register-ized (round-7 best) ----------------
__global__ __launch_bounds__(256)
void k_serial(const uint32_t* __restrict__ A1buf, const unsigned short* __restrict__ Qefbuf,
              const unsigned short* __restrict__ G1buf, const unsigned short* __restrict__ G2Tbuf,
              const float* __restrict__ gCbuf, const float* __restrict__ Gb,
              unsigned short* __restrict__ Yhi, unsigned short* __restrict__ Ylo) {
  __shared__ __align__(16) unsigned short QefL[64][72], G2TL[64][72];
  __shared__ __align__(16) unsigned short S0hi[16][72], S0lo[16][72];

  const int tid  = threadIdx.x;
  const int lane = tid & 63;
  const int w    = tid >> 6;
  const int l15  = lane & 15;
  const int quad = lane >> 4;
  const int bh   = blockIdx.x >> 2;        // (b*16 + h)
  const int iq   = blockIdx.x & 3;
  const int ibase = iq * 16;
  const int b    = bh >> 4;
  const int h    = bh & 15;
  const f32x4 z4 = {0.f, 0.f, 0.f, 0.f};

  for (int n = tid; n < 16 * 72; n += 256) { (&S0hi[0][0])[n] = 0; (&S0lo[0][0])[n] = 0; }

  float s0[4] = {0.f, 0.f, 0.f, 0.f};

  const int qRow0 = tid >> 3, qCol = (tid & 7) * 8;
  const int qRow1 = (tid + 256) >> 3;
  int4v rQv[2], rG2v[2];
  uint32_t rA[4];
  unsigned short rG1[4];
  float pg[4], pgC;
  {
    const uint32_t* pA  = A1buf + (size_t)bh * 32 * 4096;
    const uint32_t* pQ  = (const uint32_t*)Qefbuf + (size_t)bh * 32 * 2048;
    const unsigned short* pG1 = G1buf + (size_t)bh * 32 * 4096;
    const uint32_t* pG2 = (const uint32_t*)G2Tbuf + (size_t)bh * 32 * 2048;
    rQv[0]  = *(const int4v*)&pQ[tid * 4];
    rQv[1]  = *(const int4v*)&pQ[(tid + 256) * 4];
    rG2v[0] = *(const int4v*)&pG2[tid * 4];
    rG2v[1] = *(const int4v*)&pG2[(tid + 256) * 4];
#pragma unroll
    for (int r = 0; r < 4; ++r) {
      rA[r]  = pA[(w * 16 + quad * 4 + r) * 64 + ibase + l15];
      rG1[r] = pG1[(ibase + quad * 4 + r) * 64 + w * 16 + l15];
      pg[r]  = Gb[((long)b * 2048 + w * 16 + quad * 4 + r) * 1024 + h * 64 + ibase + l15];
    }
    pgC = gCbuf[(size_t)bh * 32];
  }
  __syncthreads();

#pragma unroll 1
  for (int c = 0; c < 32; ++c) {
    *(int4v*)&QefL[qRow0][qCol] = rQv[0];
    *(int4v*)&QefL[qRow1][qCol] = rQv[1];
    *(int4v*)&G2TL[qRow0][qCol] = rG2v[0];
    *(int4v*)&G2TL[qRow1][qCol] = rG2v[1];
    uint32_t a1l[4]; unsigned short g1l[4]; float pgl[4];
#pragma unroll
    for (int e = 0; e < 4; ++e) { a1l[e] = rA[e]; g1l[e] = rG1[e]; pgl[e] = pg[e]; }
    float gC = pgC;
    __syncthreads();                                   // B1

    f32x4 accO = z4, accS = z4;
#pragma unroll
    for (int ks = 0; ks < 2; ++ks) {
      bf16x8 qa  = *(const bf16x8*)&QefL[w * 16 + l15][ks * 32 + quad * 8];
      bf16x8 sh0 = *(const bf16x8*)&S0hi[l15][ks * 32 + quad * 8];
      bf16x8 sl0 = *(const bf16x8*)&S0lo[l15][ks * 32 + quad * 8];
      accO = __builtin_amdgcn_mfma_f32_16x16x32_bf16(qa, sh0, accO, 0, 0, 0);
      accO = __builtin_amdgcn_mfma_f32_16x16x32_bf16(qa, sl0, accO, 0, 0, 0);
      bf16x8 g2 = *(const bf16x8*)&G2TL[w * 16 + l15][ks * 32 + quad * 8];
      accS = __builtin_amdgcn_mfma_f32_16x16x32_bf16(sh0, g2, accS, 0, 0, 0);
      accS = __builtin_amdgcn_mfma_f32_16x16x32_bf16(sl0, g2, accS, 0, 0, 0);
    }
    {
      const int cc = (c + 1 < 32) ? c + 1 : 31;
      const uint32_t* pA  = A1buf + ((size_t)bh * 32 + cc) * 4096;
      const uint32_t* pQ  = (const uint32_t*)Qefbuf + ((size_t)bh * 32 + cc) * 2048;
      const unsigned short* pG1 = G1buf + ((size_t)bh * 32 + cc) * 4096;
      const uint32_t* pG2 = (const uint32_t*)G2Tbuf + ((size_t)bh * 32 + cc) * 2048;
      rQv[0]  = *(const int4v*)&pQ[tid * 4];
      rQv[1]  = *(const int4v*)&pQ[(tid + 256) * 4];
      rG2v[0] = *(const int4v*)&pG2[tid * 4];
      rG2v[1] = *(const int4v*)&pG2[(tid + 256) * 4];
#pragma unroll
      for (int r = 0; r < 4; ++r) {
        rA[r]  = pA[(w * 16 + quad * 4 + r) * 64 + ibase + l15];
        rG1[r] = pG1[(ibase + quad * 4 + r) * 64 + w * 16 + l15];
        pg[r]  = Gb[((long)b * 2048 + cc * 64 + w * 16 + quad * 4 + r) * 1024 + h * 64 + ibase + l15];
      }
      pgC = gCbuf[(size_t)bh * 32 + cc];
    }
    __syncthreads();                                   // B2

#pragma unroll
    for (int r = 0; r < 4; ++r) {
      int t = w * 16 + quad * 4 + r;
      float o = accO[r] + bf2f((unsigned short)(a1l[r] >> 16)) + bf2f((unsigned short)(a1l[r] & 0xffffu));
      float y = o * pgl[r];
      long ro = ((long)b * 2048 + c * 64 + t) * 1024 + h * 64 + ibase + l15;
      unsigned short hy = f2bf(y);
      Yhi[ro] = hy;
      Ylo[ro] = f2bf(y - bf2f(hy));
    }
#pragma unroll
    for (int r = 0; r < 4; ++r) {
      int i = quad * 4 + r, j = w * 16 + l15;
      float sn = gC * s0[r] + bf2f(g1l[r]) - accS[r];
      s0[r] = sn;
      uint32_t p = packsplit(sn);
      S0hi[i][j] = (unsigned short)(p >> 16);
      S0lo[i][j] = (unsigned short)(p & 0xffffu);
    }
  }
}

extern "C" void kernel_launch(void* const* d_in, const int* in_sizes, int n_in,
                              void* d_out, int out_size, void* d_ws, size_t ws_size,
                              hipStream_t stream) {
  const float* X   = (const float*)d_in[0];
  const float* Wq  = (const float*)d_in[1];
  const float* Wk  = (const float*)d_in[2];
  const float* Wv  = (const float*)d_in[3];
  const float* Wa  = (const float*)d_in[4];
  const float* ba  = (const float*)d_in[5];
  const float* Wb  = (const float*)d_in[6];
  const float* bb  = (const float*)d_in[7];
  const float* cqw = (const float*)d_in[8];
  const float* cqb = (const float*)d_in[9];
  const float* ckw = (const float*)d_in[10];
  const float* ckb = (const float*)d_in[11];
  const float* cvw = (const float*)d_in[12];
  const float* cvb = (const float*)d_in[13];
  const float* Wg  = (const float*)d_in[14];
  const float* bg  = (const float*)d_in[15];
  const float* Wo  = (const float*)d_in[16];
  float* Out = (float*)d_out;

  char* ws = (char*)d_ws;
  size_t off = 0;
  auto alloc = [&](size_t bytes) -> void* {
    void* p = ws + off;
    off += (bytes + 255) & ~(size_t)255;
    return p;
  };
  unsigned short* Xhi = (unsigned short*)alloc((size_t)MM * KK * 2);
  unsigned short* Xlo = (unsigned short*)alloc((size_t)MM * KK * 2);
  unsigned short* Whi = (unsigned short*)alloc((size_t)NCAT * KK * 2);
  unsigned short* Wlo = (unsigned short*)alloc((size_t)NCAT * KK * 2);
  float* Qb  = (float*)alloc((size_t)MM * 1024 * 4);
  float* Kb  = (float*)alloc((size_t)MM * 1024 * 4);
  float* Vb  = (float*)alloc((size_t)MM * 1024 * 4);
  float* Ab  = (float*)alloc((size_t)MM * 16 * 4);
  float* Bbf = (float*)alloc((size_t)MM * 16 * 4);
  uint32_t*       A1buf  = (uint32_t*)alloc((size_t)2048 * 4096 * 4);
  unsigned short* G1buf  = (unsigned short*)alloc((size_t)2048 * 4096 * 2);
  unsigned short* G2Tbuf = (unsigned short*)alloc((size_t)2048 * 4096 * 2);
  float*          gCbuf  = (float*)alloc((size_t)2048 * 4);
  // aliases of dead regions
  float* Gb = Out;                         // d_out doubles as G buffer until GEMM2
  unsigned short* Yhi = Xhi;               // X splits dead after GEMM1
  unsigned short* Ylo = Xlo;
  unsigned short* Qefbuf = Whi;            // Wcat dead after GEMM1
  unsigned short* Wohi = Whi;              // Wo split after k_serial consumed Qefbuf
  unsigned short* Wolo = Wlo;

  const int nX = MM * KK;
  k_split<<<nX / 8 / 256, 256, 0, stream>>>(X, Xhi, Xlo, nX);
  k_build_wcat<<<NCAT * KK / 8 / 256, 256, 0, stream>>>(Wq, Wk, Wv, Wg, Wa, Wb, Whi, Wlo);
  k_gemm<<<dim3(MM / 128, NCAT / 128), 256, 0, stream>>>(
      Xhi, Xlo, Whi, Wlo, KK, 0, Qb, Kb, Vb, Gb, Ab, Bbf, bg, ba, bb, nullptr);
  k_intra<<<NB * NH * 32, 512, 0, stream>>>(Qb, Kb, Vb, Ab, Bbf,
                                            cqw, cqb, ckw, ckb, cvw, cvb,
                                            A1buf, Qefbuf, G1buf, G2Tbuf, gCbuf);
  k_serial<<<NB * NH * 4, 256, 0, stream>>>(A1buf, Qefbuf, G1buf, G2Tbuf, gCbuf, Gb, Yhi, Ylo);
  k_split<<<1024 * 1024 / 8 / 256, 256, 0, stream>>>(Wo, Wohi, Wolo, 1024 * 1024);
  k_gemm<<<dim3(MM / 128, 1024 / 128), 256, 0, stream>>>(
      Yhi, Ylo, Wohi, Wolo, KK, 1, nullptr, nullptr, nullptr, nullptr, nullptr, nullptr,
      nullptr, nullptr, nullptr, Out);
}

// Round 11
// 634.814 us; speedup vs baseline: 1.0165x; 1.0165x over previous
//
#include <hip/hip_runtime.h>
#include <cstdint>
#include <cstddef>

// Problem constants (fixed by reference: B=4, T=2048, D=1024, H=16, DH=64, K=4)
#define TSEQ 2048
#define NB   4
#define NH   16
#define MM   (NB * TSEQ)     // 8192 rows
#define KK   1024            // inner dim for all big GEMMs
#define NCAT 4224            // 1024*4 (q,k,v,g) + 16 (a) + 16 (b) + 96 pad -> 33 tiles of 128

typedef __attribute__((ext_vector_type(8))) __bf16 bf16x8;
typedef __attribute__((ext_vector_type(4))) float f32x4;
typedef __attribute__((ext_vector_type(4))) int   int4v;

__device__ __forceinline__ unsigned short f2bf(float f) {
  unsigned int u = __float_as_uint(f);
  u += 0x7fffu + ((u >> 16) & 1u);          // round-to-nearest-even
  return (unsigned short)(u >> 16);
}
__device__ __forceinline__ float bf2f(unsigned short h) {
  return __uint_as_float(((unsigned int)h) << 16);
}
__device__ __forceinline__ float sigmoidf_(float x) { return 1.0f / (1.0f + expf(-x)); }
__device__ __forceinline__ float siluf_(float x)    { return x / (1.0f + expf(-x)); }

__device__ __forceinline__ uint32_t packsplit(float x) {
  unsigned short h = f2bf(x);
  unsigned short l = f2bf(x - bf2f(h));
  return ((uint32_t)h << 16) | (uint32_t)l;
}

union BF8 { bf16x8 v; unsigned short s[8]; };

__device__ __forceinline__ void frag_from_packed(const uint32_t* p, bf16x8& hi, bf16x8& lo) {
  int4v a = *(const int4v*)p;
  int4v b = *(const int4v*)(p + 4);
  BF8 H, L;
#pragma unroll
  for (int e = 0; e < 4; ++e) {
    uint32_t ua = ((const uint32_t*)&a)[e];
    uint32_t ub = ((const uint32_t*)&b)[e];
    H.s[e]     = (unsigned short)(ua >> 16);
    L.s[e]     = (unsigned short)(ua & 0xffffu);
    H.s[e + 4] = (unsigned short)(ub >> 16);
    L.s[e + 4] = (unsigned short)(ub & 0xffffu);
  }
  hi = H.v; lo = L.v;
}

__device__ __forceinline__ f32x4 mfma3(bf16x8 ah, bf16x8 al, bf16x8 bh, bf16x8 bl, f32x4 acc) {
  acc = __builtin_amdgcn_mfma_f32_16x16x32_bf16(ah, bh, acc, 0, 0, 0);
  acc = __builtin_amdgcn_mfma_f32_16x16x32_bf16(ah, bl, acc, 0, 0, 0);
  acc = __builtin_amdgcn_mfma_f32_16x16x32_bf16(al, bh, acc, 0, 0, 0);
  return acc;
}

// ---------------- split fp32 -> bf16 hi/lo (vectorized x8) ----------------
__global__ void k_split(const float* __restrict__ x, unsigned short* __restrict__ hi,
                        unsigned short* __restrict__ lo, int n) {
  int idx = (blockIdx.x * blockDim.x + threadIdx.x) * 8;
  if (idx >= n) return;
  float v[8];
  *(float4*)&v[0] = *(const float4*)(x + idx);
  *(float4*)&v[4] = *(const float4*)(x + idx + 4);
  unsigned short hs[8], ls[8];
#pragma unroll
  for (int e = 0; e < 8; ++e) {
    unsigned short h = f2bf(v[e]);
    hs[e] = h;
    ls[e] = f2bf(v[e] - bf2f(h));
  }
  *(int4v*)(hi + idx) = *(const int4v*)hs;
  *(int4v*)(lo + idx) = *(const int4v*)ls;
}

// ---------------- build Wcat hi/lo (vectorized x8) ----------------
__global__ void k_build_wcat(const float* __restrict__ Wq, const float* __restrict__ Wk,
                             const float* __restrict__ Wv, const float* __restrict__ Wg,
                             const float* __restrict__ Wa, const float* __restrict__ Wb,
                             unsigned short* __restrict__ hi, unsigned short* __restrict__ lo) {
  int idx = (blockIdx.x * blockDim.x + threadIdx.x) * 8;
  if (idx >= NCAT * KK) return;
  int row = idx >> 10, col = idx & 1023;
  const float* src = nullptr;
  if      (row < 1024) src = Wq + idx;
  else if (row < 2048) src = Wk + (idx - 1024 * 1024);
  else if (row < 3072) src = Wv + (idx - 2048 * 1024);
  else if (row < 4096) src = Wg + (idx - 3072 * 1024);
  else if (row < 4112) src = Wa + (row - 4096) * 1024 + col;
  else if (row < 4128) src = Wb + (row - 4112) * 1024 + col;
  float v[8];
  if (src) {
    *(float4*)&v[0] = *(const float4*)src;
    *(float4*)&v[4] = *(const float4*)(src + 4);
  } else {
#pragma unroll
    for (int e = 0; e < 8; ++e) v[e] = 0.0f;
  }
  unsigned short hs[8], ls[8];
#pragma unroll
  for (int e = 0; e < 8; ++e) {
    unsigned short h = f2bf(v[e]);
    hs[e] = h;
    ls[e] = f2bf(v[e] - bf2f(h));
  }
  *(int4v*)(hi + idx) = *(const int4v*)hs;
  *(int4v*)(lo + idx) = *(const int4v*)ls;
}

// ---------------- split-bf16 MFMA GEMM (round-9 best: LSTR=32; the 40-pad DOUBLED
// conflicts and cost 4% — b128 wave bank pattern disproved the pad model) ----------------
__global__ __launch_bounds__(256, 2)
void k_gemm(const unsigned short* __restrict__ Ahi, const unsigned short* __restrict__ Alo,
            const unsigned short* __restrict__ Bhi, const unsigned short* __restrict__ Blo,
            int Kdim, int mode,
            float* __restrict__ Qb, float* __restrict__ Kb, float* __restrict__ Vb,
            float* __restrict__ Gb, float* __restrict__ Ab, float* __restrict__ Bbuf,
            const float* __restrict__ bg, const float* __restrict__ ba, const float* __restrict__ bb,
            float* __restrict__ Out) {
  __shared__ __align__(16) unsigned short As_hi[128 * 32];
  __shared__ __align__(16) unsigned short As_lo[128 * 32];
  __shared__ __align__(16) unsigned short Bs_hi[128 * 32];
  __shared__ __align__(16) unsigned short Bs_lo[128 * 32];

  const int tid  = threadIdx.x;
  const int lane = tid & 63;
  const int l15  = lane & 15;
  const int quad = lane >> 4;
  const int wid  = tid >> 6;
  const int wm   = (wid >> 1) * 64;
  const int wn   = (wid & 1) * 64;
  const int m0   = blockIdx.x * 128;
  const int n0   = blockIdx.y * 128;
  const int srow = tid >> 2;
  const int skc  = (tid & 3) * 8;

  f32x4 acc[4][4];
  f32x4 zero4 = {0.f, 0.f, 0.f, 0.f};
#pragma unroll
  for (int i = 0; i < 4; ++i)
#pragma unroll
    for (int j = 0; j < 4; ++j) acc[i][j] = zero4;

  const unsigned short* pa0 = Ahi + (size_t)(m0 + srow) * Kdim + skc;
  const unsigned short* pa1 = Ahi + (size_t)(m0 + srow + 64) * Kdim + skc;
  const unsigned short* pa2 = Alo + (size_t)(m0 + srow) * Kdim + skc;
  const unsigned short* pa3 = Alo + (size_t)(m0 + srow + 64) * Kdim + skc;
  const unsigned short* pb0 = Bhi + (size_t)(n0 + srow) * Kdim + skc;
  const unsigned short* pb1 = Bhi + (size_t)(n0 + srow + 64) * Kdim + skc;
  const unsigned short* pb2 = Blo + (size_t)(n0 + srow) * Kdim + skc;
  const unsigned short* pb3 = Blo + (size_t)(n0 + srow + 64) * Kdim + skc;

  for (int kt = 0; kt < Kdim; kt += 32) {
    int4v va0 = *(const int4v*)(pa0 + kt);
    int4v va1 = *(const int4v*)(pa1 + kt);
    int4v va2 = *(const int4v*)(pa2 + kt);
    int4v va3 = *(const int4v*)(pa3 + kt);
    int4v vb0 = *(const int4v*)(pb0 + kt);
    int4v vb1 = *(const int4v*)(pb1 + kt);
    int4v vb2 = *(const int4v*)(pb2 + kt);
    int4v vb3 = *(const int4v*)(pb3 + kt);
    __syncthreads();
    *(int4v*)&As_hi[srow * 32 + skc]        = va0;
    *(int4v*)&As_hi[(srow + 64) * 32 + skc] = va1;
    *(int4v*)&As_lo[srow * 32 + skc]        = va2;
    *(int4v*)&As_lo[(srow + 64) * 32 + skc] = va3;
    *(int4v*)&Bs_hi[srow * 32 + skc]        = vb0;
    *(int4v*)&Bs_hi[(srow + 64) * 32 + skc] = vb1;
    *(int4v*)&Bs_lo[srow * 32 + skc]        = vb2;
    *(int4v*)&Bs_lo[(srow + 64) * 32 + skc] = vb3;
    __syncthreads();

    bf16x8 ah[4], al[4], bh[4], bl[4];
#pragma unroll
    for (int f = 0; f < 4; ++f) {
      int ra = (wm + f * 16 + l15) * 32 + quad * 8;
      ah[f] = *(const bf16x8*)&As_hi[ra];
      al[f] = *(const bf16x8*)&As_lo[ra];
      int rb = (wn + f * 16 + l15) * 32 + quad * 8;
      bh[f] = *(const bf16x8*)&Bs_hi[rb];
      bl[f] = *(const bf16x8*)&Bs_lo[rb];
    }
#pragma unroll
    for (int mf = 0; mf < 4; ++mf)
#pragma unroll
      for (int nf = 0; nf < 4; ++nf) {
        acc[mf][nf] = __builtin_amdgcn_mfma_f32_16x16x32_bf16(ah[mf], bh[nf], acc[mf][nf], 0, 0, 0);
        acc[mf][nf] = __builtin_amdgcn_mfma_f32_16x16x32_bf16(ah[mf], bl[nf], acc[mf][nf], 0, 0, 0);
        acc[mf][nf] = __builtin_amdgcn_mfma_f32_16x16x32_bf16(al[mf], bh[nf], acc[mf][nf], 0, 0, 0);
      }
  }

#pragma unroll
  for (int mf = 0; mf < 4; ++mf) {
    int rowb = m0 + wm + mf * 16 + quad * 4;
#pragma unroll
    for (int nf = 0; nf < 4; ++nf) {
      int col = n0 + wn + nf * 16 + l15;
      f32x4 v = acc[mf][nf];
      if (mode == 1) {
#pragma unroll
        for (int r = 0; r < 4; ++r) Out[(size_t)(rowb + r) * 1024 + col] = v[r];
      } else {
        if (col < 1024) {
#pragma unroll
          for (int r = 0; r < 4; ++r) Qb[(size_t)(rowb + r) * 1024 + col] = v[r];
        } else if (col < 2048) {
          int c = col - 1024;
#pragma unroll
          for (int r = 0; r < 4; ++r) Kb[(size_t)(rowb + r) * 1024 + c] = v[r];
        } else if (col < 3072) {
          int c = col - 2048;
#pragma unroll
          for (int r = 0; r < 4; ++r) Vb[(size_t)(rowb + r) * 1024 + c] = v[r];
        } else if (col < 4096) {
          int c = col - 3072;
          float bgc = bg[c];
#pragma unroll
          for (int r = 0; r < 4; ++r) {
            float x = v[r] + bgc;
            Gb[(size_t)(rowb + r) * 1024 + c] = siluf_(x);
          }
        } else if (col < 4112) {
          int c = col - 4096;
          float bac = ba[c];
#pragma unroll
          for (int r = 0; r < 4; ++r) Ab[(size_t)(rowb + r) * 16 + c] = sigmoidf_(v[r] + bac);
        } else if (col < 4128) {
          int c = col - 4112;
          float bbc = bb[c];
#pragma unroll
          for (int r = 0; r < 4; ++r) Bbuf[(size_t)(rowb + r) * 16 + c] = sigmoidf_(v[r] + bbc);
        }
      }
    }
  }
}

// ---------------- k_intra: round-7 best (512 threads, grid 2048) ----------------
__global__ __launch_bounds__(512)
void k_intra(const float* __restrict__ Qb, const float* __restrict__ Kb,
             const float* __restrict__ Vb,
             const float* __restrict__ Ab, const float* __restrict__ Bb,
             const float* __restrict__ cqw, const float* __restrict__ cqb,
             const float* __restrict__ ckw, const float* __restrict__ ckb,
             const float* __restrict__ cvw, const float* __restrict__ cvb,
             uint32_t* __restrict__ A1buf, unsigned short* __restrict__ Qefbuf,
             unsigned short* __restrict__ G1buf, unsigned short* __restrict__ G2Tbuf,
             float* __restrict__ gCbuf) {
  __shared__ __align__(16) unsigned short Khi[64][72], Klo[64][72];
  __shared__ __align__(16) unsigned short Qhi[64][72], Qlo[64][72];
  __shared__ float Vf[64][65];
  __shared__ float Rf[64][65];
  __shared__ float Mm[64][68];
  __shared__ __align__(16) unsigned short Atthi[64][72];
  __shared__ __align__(16) uint32_t u0T[64][68], RTp[64][68];
  __shared__ __align__(16) unsigned short KwThi[64][72], KwTlo[64][72];
  __shared__ float lgs[64], gas[64], bss[64], wvs[64], ins[64];

  const int tid  = threadIdx.x;
  const int lane = tid & 63;
  const int w8   = tid >> 6;
  const int ws   = w8 & 3;
  const int hs   = w8 >> 2;
  const int l15  = lane & 15;
  const int quad = lane >> 4;
  const int bid  = blockIdx.x;
  const int c    = bid & 31;
  const int h    = (bid >> 5) & 15;
  const int b    = bid >> 9;
  const size_t ci = (size_t)bid;
  const int t0   = c * 64;
  const long rowBase = (long)b * 2048 + t0;
  const int ch   = h * 64 + lane;
  const f32x4 z4 = {0.f, 0.f, 0.f, 0.f};

  {
    long gr = (rowBase + lane) * 16 + h;
    float av = Ab[gr], bv = Bb[gr];
    float x = log2f(av);
#pragma unroll
    for (int off = 1; off < 64; off <<= 1) {
      float y = __shfl_up(x, off);
      if (lane >= off) x += y;
    }
    float l63 = __shfl(x, 63);
    lgs[lane] = x;
    gas[lane] = exp2f(x);
    bss[lane] = bv;
    wvs[lane] = exp2f(l63 - x) * bv;
  }

  {
    const float kc0 = ckw[ch * 4], kc1 = ckw[ch * 4 + 1], kc2 = ckw[ch * 4 + 2], kc3 = ckw[ch * 4 + 3], kcbv = ckb[ch];
    const float qc0 = cqw[ch * 4], qc1 = cqw[ch * 4 + 1], qc2 = cqw[ch * 4 + 2], qc3 = cqw[ch * 4 + 3], qcbv = cqb[ch];
    const float vc0 = cvw[ch * 4], vc1 = cvw[ch * 4 + 1], vc2 = cvw[ch * 4 + 2], vc3 = cvw[ch * 4 + 3], vcbv = cvb[ch];
    const int tb = t0 + w8 * 8;
    float kw0, kw1, kw2, qw0, qw1, qw2, vw0, vw1, vw2;
    {
      float kx[3], qx[3], vx[3];
#pragma unroll
      for (int d = 0; d < 3; ++d) {
        int tt = tb - 3 + d;
        float a = 0.f, bq = 0.f, cv = 0.f;
        if (tt >= 0) {
          long ro = ((long)b * 2048 + tt) * 1024 + ch;
          a = Kb[ro]; bq = Qb[ro]; cv = Vb[ro];
        }
        kx[d] = a; qx[d] = bq; vx[d] = cv;
      }
      kw0 = kx[0]; kw1 = kx[1]; kw2 = kx[2];
      qw0 = qx[0]; qw1 = qx[1]; qw2 = qx[2];
      vw0 = vx[0]; vw1 = vx[1]; vw2 = vx[2];
    }
#pragma unroll
    for (int lt = 0; lt < 8; ++lt) {
      const int s = w8 * 8 + lt;
      const long ro = (rowBase + s) * 1024 + ch;
      float kr = Kb[ro], qr = Qb[ro], vr = Vb[ro];
      float kcv = kcbv + kc0 * kw0 + kc1 * kw1 + kc2 * kw2 + kc3 * kr;
      float qcv = qcbv + qc0 * qw0 + qc1 * qw1 + qc2 * qw2 + qc3 * qr;
      float vcv = vcbv + vc0 * vw0 + vc1 * vw1 + vc2 * vw2 + vc3 * vr;
      kw0 = kw1; kw1 = kw2; kw2 = kr;
      qw0 = qw1; qw1 = qw2; qw2 = qr;
      vw0 = vw1; vw1 = vw2; vw2 = vr;
      float kv = siluf_(kcv), qv = siluf_(qcv), vv = siluf_(vcv);
      uint32_t kp_ = packsplit(kv);
      uint32_t qp_ = packsplit(qv);
      Khi[s][lane] = (unsigned short)(kp_ >> 16); Klo[s][lane] = (unsigned short)(kp_ & 0xffffu);
      Qhi[s][lane] = (unsigned short)(qp_ >> 16); Qlo[s][lane] = (unsigned short)(qp_ & 0xffffu);
      Vf[s][lane] = vv;
    }
  }
  __syncthreads();                                     // B1

  f32x4 accT[4];
#pragma unroll
  for (int nt = 0; nt < 4; ++nt) accT[nt] = z4;
#pragma unroll
  for (int ks = 0; ks < 2; ++ks) {
    bf16x8 ah, al;
    if (hs == 0) {
      ah = *(const bf16x8*)&Khi[ws * 16 + l15][ks * 32 + quad * 8];
      al = *(const bf16x8*)&Klo[ws * 16 + l15][ks * 32 + quad * 8];
    } else {
      ah = *(const bf16x8*)&Qhi[ws * 16 + l15][ks * 32 + quad * 8];
      al = *(const bf16x8*)&Qlo[ws * 16 + l15][ks * 32 + quad * 8];
    }
#pragma unroll
    for (int nt = 0; nt < 4; ++nt) {
      bf16x8 bh = *(const bf16x8*)&Khi[nt * 16 + l15][ks * 32 + quad * 8];
      bf16x8 bl = *(const bf16x8*)&Klo[nt * 16 + l15][ks * 32 + quad * 8];
      accT[nt] = mfma3(ah, al, bh, bl, accT[nt]);
    }
  }
  if (hs == 0) {
#pragma unroll
    for (int nt = 0; nt < 4; ++nt)
      if (nt == ws) {
#pragma unroll
        for (int r = 0; r < 4; ++r)
          if (l15 == quad * 4 + r) ins[nt * 16 + l15] = rsqrtf(fmaxf(accT[nt][r], 1e-24f));
      }
  }
  __syncthreads();                                     // B2

  {
    if (hs == 0) {
#pragma unroll
      for (int nt = 0; nt < 4; ++nt) {
        int sc = nt * 16 + l15;
        float insc = ins[sc], lgc = lgs[sc], bsc = bss[sc];
#pragma unroll
        for (int r = 0; r < 4; ++r) {
          int sr = ws * 16 + quad * 4 + r;
          Mm[sr][sc] = (sc < sr) ? exp2f(lgs[sr] - lgc) * bsc * ins[sr] * insc * accT[nt][r] : 0.f;
        }
      }
    } else {
#pragma unroll
      for (int nt = 0; nt < 4; ++nt) {
        int sc = nt * 16 + l15;
        float insc = ins[sc], lgc = lgs[sc], bsc = bss[sc];
#pragma unroll
        for (int r = 0; r < 4; ++r) {
          int sr = ws * 16 + quad * 4 + r;
          Atthi[sr][sc] = f2bf((sc <= sr) ? exp2f(lgs[sr] - lgc) * bsc * insc * accT[nt][r] : 0.f);
        }
      }
    }
    int s = w8 * 8 + (lane & 7);
    int jb = (lane >> 3) * 8;
    float rsc = gas[s] * ins[s];
    float wsc = wvs[s] * ins[s];
    BF8 H0, L0;
    H0.v = *(const bf16x8*)&Khi[s][jb];
    L0.v = *(const bf16x8*)&Klo[s][jb];
#pragma unroll
    for (int e = 0; e < 8; ++e) {
      float kv = bf2f(H0.s[e]) + bf2f(L0.s[e]);
      Rf[s][jb + e] = kv * rsc;
      uint32_t p0 = packsplit(kv * wsc);
      KwThi[jb + e][s] = (unsigned short)(p0 >> 16);
      KwTlo[jb + e][s] = (unsigned short)(p0 & 0xffffu);
    }
  }
  if (tid == 0) gCbuf[ci] = gas[63];
  __syncthreads();                                     // B3

  if (w8 < 2) {
    float* RHS = (w8 == 0) ? &Vf[0][0] : &Rf[0][0];
    const int i = lane;
    float u[64];
#pragma unroll
    for (int d = 0; d < 4; ++d) {
      const int base = d * 16;
#pragma unroll
      for (int r2 = 0; r2 < 16; ++r2) {
        const int s = base + r2;
        float acc = RHS[s * 65 + i];
#pragma unroll
        for (int r = 0; r < r2; ++r) acc = fmaf(-Mm[s][base + r], u[base + r], acc);
        u[s] = acc;
        RHS[s * 65 + i] = acc;
      }
      if (d < 3) {
#pragma unroll 1
        for (int s = base + 16; s < 64; ++s) {
          f32x4 m0 = *(const f32x4*)&Mm[s][base];
          f32x4 m1 = *(const f32x4*)&Mm[s][base + 4];
          f32x4 m2 = *(const f32x4*)&Mm[s][base + 8];
          f32x4 m3 = *(const f32x4*)&Mm[s][base + 12];
          float a0 = m0[0] * u[base + 0] + m0[1] * u[base + 1] + m0[2] * u[base + 2] + m0[3] * u[base + 3];
          float a1 = m1[0] * u[base + 4] + m1[1] * u[base + 5] + m1[2] * u[base + 6] + m1[3] * u[base + 7];
          float a2 = m2[0] * u[base + 8] + m2[1] * u[base + 9] + m2[2] * u[base + 10] + m2[3] * u[base + 11];
          float a3 = m3[0] * u[base + 12] + m3[1] * u[base + 13] + m3[2] * u[base + 14] + m3[3] * u[base + 15];
          RHS[s * 65 + i] = RHS[s * 65 + i] - ((a0 + a1) + (a2 + a3));
        }
      }
    }
  }
  __syncthreads();                                     // B4

#pragma unroll
  for (int r = 0; r < 8; ++r) {
    int i = w8 * 8 + r;
    u0T[i][lane] = packsplit(Vf[lane][i]);
    RTp[i][lane] = packsplit(Rf[lane][i]);
  }
  __syncthreads();                                     // B5

  if (hs == 0) {
    {
      f32x4 acc[4];
#pragma unroll
      for (int nt = 0; nt < 4; ++nt) acc[nt] = z4;
#pragma unroll
      for (int ks = 0; ks < 2; ++ks) {
        bf16x8 ta = *(const bf16x8*)&Atthi[ws * 16 + l15][ks * 32 + quad * 8];
#pragma unroll
        for (int nt = 0; nt < 4; ++nt) {
          bf16x8 uh, ul;
          frag_from_packed(&u0T[nt * 16 + l15][ks * 32 + quad * 8], uh, ul);
          acc[nt] = __builtin_amdgcn_mfma_f32_16x16x32_bf16(ta, uh, acc[nt], 0, 0, 0);
          acc[nt] = __builtin_amdgcn_mfma_f32_16x16x32_bf16(ta, ul, acc[nt], 0, 0, 0);
        }
      }
#pragma unroll
      for (int nt = 0; nt < 4; ++nt)
#pragma unroll
        for (int r = 0; r < 4; ++r) {
          int t = ws * 16 + quad * 4 + r, i = nt * 16 + l15;
          A1buf[ci * 4096 + t * 64 + i] = packsplit(acc[nt][r]);
        }
    }
    {
      f32x4 acc[4];
#pragma unroll
      for (int nt = 0; nt < 4; ++nt) acc[nt] = z4;
#pragma unroll
      for (int ks = 0; ks < 2; ++ks) {
        bf16x8 ta = *(const bf16x8*)&Atthi[ws * 16 + l15][ks * 32 + quad * 8];
#pragma unroll
        for (int nt = 0; nt < 4; ++nt) {
          bf16x8 rh, rl;
          frag_from_packed(&RTp[nt * 16 + l15][ks * 32 + quad * 8], rh, rl);
          acc[nt] = __builtin_amdgcn_mfma_f32_16x16x32_bf16(ta, rh, acc[nt], 0, 0, 0);
          acc[nt] = __builtin_amdgcn_mfma_f32_16x16x32_bf16(ta, rl, acc[nt], 0, 0, 0);
        }
      }
#pragma unroll
      for (int nt = 0; nt < 4; ++nt)
#pragma unroll
        for (int r = 0; r < 4; ++r) {
          int t = ws * 16 + quad * 4 + r, j = nt * 16 + l15;
          float q = bf2f(Qhi[t][j]) + bf2f(Qlo[t][j]);
          Qefbuf[ci * 4096 + t * 64 + j] = f2bf(gas[t] * q - acc[nt][r]);
        }
    }
  } else {
    {
      f32x4 acc[4];
#pragma unroll
      for (int nt = 0; nt < 4; ++nt) acc[nt] = z4;
#pragma unroll
      for (int ks = 0; ks < 2; ++ks) {
        bf16x8 uh, ul;
        frag_from_packed(&u0T[ws * 16 + l15][ks * 32 + quad * 8], uh, ul);
#pragma unroll
        for (int nt = 0; nt < 4; ++nt) {
          bf16x8 kh = *(const bf16x8*)&KwThi[nt * 16 + l15][ks * 32 + quad * 8];
          bf16x8 kl = *(const bf16x8*)&KwTlo[nt * 16 + l15][ks * 32 + quad * 8];
          acc[nt] = mfma3(uh, ul, kh, kl, acc[nt]);
        }
      }
#pragma unroll
      for (int nt = 0; nt < 4; ++nt)
#pragma unroll
        for (int r = 0; r < 4; ++r) {
          int i = ws * 16 + quad * 4 + r, j = nt * 16 + l15;
          G1buf[ci * 4096 + i * 64 + j] = f2bf(acc[nt][r]);
        }
    }
    {
      f32x4 acc[4];
#pragma unroll
      for (int nt = 0; nt < 4; ++nt) acc[nt] = z4;
#pragma unroll
      for (int ks = 0; ks < 2; ++ks) {
        bf16x8 rh, rl;
        frag_from_packed(&RTp[ws * 16 + l15][ks * 32 + quad * 8], rh, rl);
#pragma unroll
        for (int nt = 0; nt < 4; ++nt) {
          bf16x8 kh = *(const bf16x8*)&KwThi[nt * 16 + l15][ks * 32 + quad * 8];
          bf16x8 kl = *(const bf16x8*)&KwTlo[nt * 16 + l15][ks * 32 + quad * 8];
          acc[nt] = mfma3(rh, rl, kh, kl, acc[nt]);
        }
      }
#pragma unroll
      for (int nt = 0; nt < 4; ++nt) {
        int j = nt * 16 + l15;
        int mb = ws * 16 + quad * 4;
        uint32_t lo32 = (uint32_t)f2bf(acc[nt][0]) | ((uint32_t)f2bf(acc[nt][1]) << 16);
        uint32_t hi32 = (uint32_t)f2bf(acc[nt][2]) | ((uint32_t)f2bf(acc[nt][3]) << 16);
        uint32_t* dst = (uint32_t*)&G2Tbuf[ci * 4096 + j * 64 + mb];
        dst[0] = lo32; dst[1] = hi32;
      }
    }
  }
}

// ---------------- k_serial: 32-step recurrence, row-split 4x, register-ized (round-7 best) ----------------
__global__ __launch_bounds__(256)
void k_serial(const uint32_t* __restrict__ A1buf, const unsigned short* __restrict__ Qefbuf,
              const unsigned short* __restrict__ G1buf, const unsigned short* __restrict__ G2Tbuf,
              const float* __restrict__ gCbuf, const float* __restrict__ Gb,
              unsigned short* __restrict__ Yhi, unsigned short* __restrict__ Ylo) {
  __shared__ __align__(16) unsigned short QefL[64][72], G2TL[64][72];
  __shared__ __align__(16) unsigned short S0hi[16][72], S0lo[16][72];

  const int tid  = threadIdx.x;
  const int lane = tid & 63;
  const int w    = tid >> 6;
  const int l15  = lane & 15;
  const int quad = lane >> 4;
  const int bh   = blockIdx.x >> 2;        // (b*16 + h)
  const int iq   = blockIdx.x & 3;
  const int ibase = iq * 16;
  const int b    = bh >> 4;
  const int h    = bh & 15;
  const f32x4 z4 = {0.f, 0.f, 0.f, 0.f};

  for (int n = tid; n < 16 * 72; n += 256) { (&S0hi[0][0])[n] = 0; (&S0lo[0][0])[n] = 0; }

  float s0[4] = {0.f, 0.f, 0.f, 0.f};

  const int qRow0 = tid >> 3, qCol = (tid & 7) * 8;
  const int qRow1 = (tid + 256) >> 3;
  int4v rQv[2], rG2v[2];
  uint32_t rA[4];
  unsigned short rG1[4];
  float pg[4], pgC;
  {
    const uint32_t* pA  = A1buf + (size_t)bh * 32 * 4096;
    const uint32_t* pQ  = (const uint32_t*)Qefbuf + (size_t)bh * 32 * 2048;
    const unsigned short* pG1 = G1buf + (size_t)bh * 32 * 4096;
    const uint32_t* pG2 = (const uint32_t*)G2Tbuf + (size_t)bh * 32 * 2048;
    rQv[0]  = *(const int4v*)&pQ[tid * 4];
    rQv[1]  = *(const int4v*)&pQ[(tid + 256) * 4];
    rG2v[0] = *(const int4v*)&pG2[tid * 4];
    rG2v[1] = *(const int4v*)&pG2[(tid + 256) * 4];
#pragma unroll
    for (int r = 0; r < 4; ++r) {
      rA[r]  = pA[(w * 16 + quad * 4 + r) * 64 + ibase + l15];
      rG1[r] = pG1[(ibase + quad * 4 + r) * 64 + w * 16 + l15];
      pg[r]  = Gb[((long)b * 2048 + w * 16 + quad * 4 + r) * 1024 + h * 64 + ibase + l15];
    }
    pgC = gCbuf[(size_t)bh * 32];
  }
  __syncthreads();

#pragma unroll 1
  for (int c = 0; c < 32; ++c) {
    *(int4v*)&QefL[qRow0][qCol] = rQv[0];
    *(int4v*)&QefL[qRow1][qCol] = rQv[1];
    *(int4v*)&G2TL[qRow0][qCol] = rG2v[0];
    *(int4v*)&G2TL[qRow1][qCol] = rG2v[1];
    uint32_t a1l[4]; unsigned short g1l[4]; float pgl[4];
#pragma unroll
    for (int e = 0; e < 4; ++e) { a1l[e] = rA[e]; g1l[e] = rG1[e]; pgl[e] = pg[e]; }
    float gC = pgC;
    __syncthreads();                                   // B1

    f32x4 accO = z4, accS = z4;
#pragma unroll
    for (int ks = 0; ks < 2; ++ks) {
      bf16x8 qa  = *(const bf16x8*)&QefL[w * 16 + l15][ks * 32 + quad * 8];
      bf16x8 sh0 = *(const bf16x8*)&S0hi[l15][ks * 32 + quad * 8];
      bf16x8 sl0 = *(const bf16x8*)&S0lo[l15][ks * 32 + quad * 8];
      accO = __builtin_amdgcn_mfma_f32_16x16x32_bf16(qa, sh0, accO, 0, 0, 0);
      accO = __builtin_amdgcn_mfma_f32_16x16x32_bf16(qa, sl0, accO, 0, 0, 0);
      bf16x8 g2 = *(const bf16x8*)&G2TL[w * 16 + l15][ks * 32 + quad * 8];
      accS = __builtin_amdgcn_mfma_f32_16x16x32_bf16(sh0, g2, accS, 0, 0, 0);
      accS = __builtin_amdgcn_mfma_f32_16x16x32_bf16(sl0, g2, accS, 0, 0, 0);
    }
    {
      const int cc = (c + 1 < 32) ? c + 1 : 31;
      const uint32_t* pA  = A1buf + ((size_t)bh * 32 + cc) * 4096;
      const uint32_t* pQ  = (const uint32_t*)Qefbuf + ((size_t)bh * 32 + cc) * 2048;
      const unsigned short* pG1 = G1buf + ((size_t)bh * 32 + cc) * 4096;
      const uint32_t* pG2 = (const uint32_t*)G2Tbuf + ((size_t)bh * 32 + cc) * 2048;
      rQv[0]  = *(const int4v*)&pQ[tid * 4];
      rQv[1]  = *(const int4v*)&pQ[(tid + 256) * 4];
      rG2v[0] = *(const int4v*)&pG2[tid * 4];
      rG2v[1] = *(const int4v*)&pG2[(tid + 256) * 4];
#pragma unroll
      for (int r = 0; r < 4; ++r) {
        rA[r]  = pA[(w * 16 + quad * 4 + r) * 64 + ibase + l15];
        rG1[r] = pG1[(ibase + quad * 4 + r) * 64 + w * 16 + l15];
        pg[r]  = Gb[((long)b * 2048 + cc * 64 + w * 16 + quad * 4 + r) * 1024 + h * 64 + ibase + l15];
      }
      pgC = gCbuf[(size_t)bh * 32 + cc];
    }
    __syncthreads();                                   // B2

#pragma unroll
    for (int r = 0; r < 4; ++r) {
      int t = w * 16 + quad * 4 + r;
      float o = accO[r] + bf2f((unsigned short)(a1l[r] >> 16)) + bf2f((unsigned short)(a1l[r] & 0xffffu));
      float y = o * pgl[r];
      long ro = ((long)b * 2048 + c * 64 + t) * 1024 + h * 64 + ibase + l15;
      unsigned short hy = f2bf(y);
      Yhi[ro] = hy;
      Ylo[ro] = f2bf(y - bf2f(hy));
    }
#pragma unroll
    for (int r = 0; r < 4; ++r) {
      int i = quad * 4 + r, j = w * 16 + l15;
      float sn = gC * s0[r] + bf2f(g1l[r]) - accS[r];
      s0[r] = sn;
      uint32_t p = packsplit(sn);
      S0hi[i][j] = (unsigned short)(p >> 16);
      S0lo[i][j] = (unsigned short)(p & 0xffffu);
    }
  }
}

extern "C" void kernel_launch(void* const* d_in, const int* in_sizes, int n_in,
                              void* d_out, int out_size, void* d_ws, size_t ws_size,
                              hipStream_t stream) {
  const float* X   = (const float*)d_in[0];
  const float* Wq  = (const float*)d_in[1];
  const float* Wk  = (const float*)d_in[2];
  const float* Wv  = (const float*)d_in[3];
  const float* Wa  = (const float*)d_in[4];
  const float* ba  = (const float*)d_in[5];
  const float* Wb  = (const float*)d_in[6];
  const float* bb  = (const float*)d_in[7];
  const float* cqw = (const float*)d_in[8];
  const float* cqb = (const float*)d_in[9];
  const float* ckw = (const float*)d_in[10];
  const float* ckb = (const float*)d_in[11];
  const float* cvw = (const float*)d_in[12];
  const float* cvb = (const float*)d_in[13];
  const float* Wg  = (const float*)d_in[14];
  const float* bg  = (const float*)d_in[15];
  const float* Wo  = (const float*)d_in[16];
  float* Out = (float*)d_out;

  char* ws = (char*)d_ws;
  size_t off = 0;
  auto alloc = [&](size_t bytes) -> void* {
    void* p = ws + off;
    off += (bytes + 255) & ~(size_t)255;
    return p;
  };
  unsigned short* Xhi = (unsigned short*)alloc((size_t)MM * KK * 2);
  unsigned short* Xlo = (unsigned short*)alloc((size_t)MM * KK * 2);
  unsigned short* Whi = (unsigned short*)alloc((size_t)NCAT * KK * 2);
  unsigned short* Wlo = (unsigned short*)alloc((size_t)NCAT * KK * 2);
  float* Qb  = (float*)alloc((size_t)MM * 1024 * 4);
  float* Kb  = (float*)alloc((size_t)MM * 1024 * 4);
  float* Vb  = (float*)alloc((size_t)MM * 1024 * 4);
  float* Ab  = (float*)alloc((size_t)MM * 16 * 4);
  float* Bbf = (float*)alloc((size_t)MM * 16 * 4);
  uint32_t*       A1buf  = (uint32_t*)alloc((size_t)2048 * 4096 * 4);
  unsigned short* G1buf  = (unsigned short*)alloc((size_t)2048 * 4096 * 2);
  unsigned short* G2Tbuf = (unsigned short*)alloc((size_t)2048 * 4096 * 2);
  float*          gCbuf  = (float*)alloc((size_t)2048 * 4);
  // aliases of dead regions
  float* Gb = Out;                         // d_out doubles as G buffer until GEMM2
  unsigned short* Yhi = Xhi;               // X splits dead after GEMM1
  unsigned short* Ylo = Xlo;
  unsigned short* Qefbuf = Whi;            // Wcat dead after GEMM1
  unsigned short* Wohi = Whi;              // Wo split after k_serial consumed Qefbuf
  unsigned short* Wolo = Wlo;

  const int nX = MM * KK;
  k_split<<<nX / 8 / 256, 256, 0, stream>>>(X, Xhi, Xlo, nX);
  k_build_wcat<<<NCAT * KK / 8 / 256, 256, 0, stream>>>(Wq, Wk, Wv, Wg, Wa, Wb, Whi, Wlo);
  k_gemm<<<dim3(MM / 128, NCAT / 128), 256, 0, stream>>>(
      Xhi, Xlo, Whi, Wlo, KK, 0, Qb, Kb, Vb, Gb, Ab, Bbf, bg, ba, bb, nullptr);
  k_intra<<<NB * NH * 32, 512, 0, stream>>>(Qb, Kb, Vb, Ab, Bbf,
                                            cqw, cqb, ckw, ckb, cvw, cvb,
                                            A1buf, Qefbuf, G1buf, G2Tbuf, gCbuf);
  k_serial<<<NB * NH * 4, 256, 0, stream>>>(A1buf, Qefbuf, G1buf, G2Tbuf, gCbuf, Gb, Yhi, Ylo);
  k_split<<<1024 * 1024 / 8 / 256, 256, 0, stream>>>(Wo, Wohi, Wolo, 1024 * 1024);
  k_gemm<<<dim3(MM / 128, 1024 / 128), 256, 0, stream>>>(
      Yhi, Ylo, Wohi, Wolo, KK, 1, nullptr, nullptr, nullptr, nullptr, nullptr, nullptr,
      nullptr, nullptr, nullptr, Out);
}